// Round 4
// baseline (5508.756 us; speedup 1.0000x reference)
//
#include <hip/hip_runtime.h>
#include <hip/hip_bf16.h>
#include <math.h>

typedef __bf16 bf16x8 __attribute__((ext_vector_type(8)));
typedef float f32x4 __attribute__((ext_vector_type(4)));
typedef __hip_bfloat16 bf16s;

constexpr int kB = 16, kT = 24, kN = 2048, kD = 64;
constexpr size_t kBND = (size_t)kB * kN * kD;  // 2097152

// slot types: 0 = bf16 direct (global_load_lds), 1 = f32 (cvt), 2 = bf16+bf16 add
struct Slot { const void* p0; const void* p1; int astr0, trow0, astr1, trow1, type; };
struct Slots6 { Slot s[6]; };
struct DiffSrc { const bf16s* src; bf16s* oA; bf16s* oA2; };

__device__ __forceinline__ void async_copy16(void* lds, const void* g) {
  __builtin_amdgcn_global_load_lds((const __attribute__((address_space(1))) void*)g,
                                   (__attribute__((address_space(3))) void*)lds,
                                   16, 0, 0);
}

// LDS tiles are [rows][64] bf16 staged linearly; XOR swizzle on 16B chunks:
// source chunk (tid&7)^(row&7), read chunk g^(row&7). Verified 0 conflicts (r3).

// =============== dense diffusion: both supports share one B-tile ===============
// 512 threads / 8 waves. Wave w: support sp=w&1, quadrant qd=w>>1.
// Computes S0@src^T and S1@src^T over [128 m x 128 cols], K=2048.
__global__ __launch_bounds__(512) void k_diff4(
    const bf16s* __restrict__ S0, const bf16s* __restrict__ S1,
    DiffSrc g0, DiffSrc g1, int ctPerSrc)
{
  __shared__ bf16s lA0[128 * 64];
  __shared__ bf16s lA1[128 * 64];
  __shared__ bf16s lB[128 * 64];
  const int m0 = blockIdx.x * 128;
  const int grp = blockIdx.y / ctPerSrc;
  const int c0 = (blockIdx.y - grp * ctPerSrc) * 128;
  const DiffSrc G = grp ? g1 : g0;

  const int tid = threadIdx.x, lane = tid & 63, wave = tid >> 6;
  const int sp = wave & 1, qd = wave >> 1;
  const int wm = (qd >> 1) * 64, wn = (qd & 1) * 64;
  const bf16s* lAsel = sp ? lA1 : lA0;

  f32x4 acc[4][4];
  const f32x4 zero = {0.f, 0.f, 0.f, 0.f};
#pragma unroll
  for (int i = 0; i < 4; ++i)
#pragma unroll
    for (int j = 0; j < 4; ++j) acc[i][j] = zero;

  const int ra = tid >> 3;                             // 0..63
  const int cs = ((tid & 7) ^ (ra & 7)) * 8;           // swizzled source chunk
  const int rk0 = ((lane >> 4) ^ (lane & 7)) * 8;      // swizzled read chunk ks=0
  const int rk1 = ((4 + (lane >> 4)) ^ (lane & 7)) * 8;

  for (int k0 = 0; k0 < 2048; k0 += 64) {
#pragma unroll
    for (int i = 0; i < 2; ++i)
      async_copy16(lA0 + (size_t)(i * 512 + tid) * 8,
                   S0 + (size_t)(m0 + i * 64 + ra) * 2048 + k0 + cs);
#pragma unroll
    for (int i = 0; i < 2; ++i)
      async_copy16(lA1 + (size_t)(i * 512 + tid) * 8,
                   S1 + (size_t)(m0 + i * 64 + ra) * 2048 + k0 + cs);
#pragma unroll
    for (int i = 0; i < 2; ++i)
      async_copy16(lB + (size_t)(i * 512 + tid) * 8,
                   G.src + (size_t)(c0 + i * 64 + ra) * 2048 + k0 + cs);
    __syncthreads();
#pragma unroll
    for (int ks = 0; ks < 2; ++ks) {
      const int rk = ks ? rk1 : rk0;
      bf16x8 av[4], bv[4];
#pragma unroll
      for (int f = 0; f < 4; ++f) {
        av[f] = *(const bf16x8*)(lAsel + (size_t)(wm + f * 16 + (lane & 15)) * 64 + rk);
        bv[f] = *(const bf16x8*)(lB + (size_t)(wn + f * 16 + (lane & 15)) * 64 + rk);
      }
#pragma unroll
      for (int i = 0; i < 4; ++i)
#pragma unroll
        for (int j = 0; j < 4; ++j)
          acc[i][j] = __builtin_amdgcn_mfma_f32_16x16x32_bf16(av[i], bv[j], acc[i][j], 0, 0, 0);
    }
    __syncthreads();
  }

  bf16s* out = sp ? G.oA2 : G.oA;
  const int rq = (lane >> 4) * 4, cl = lane & 15;
#pragma unroll
  for (int fm = 0; fm < 4; ++fm)
#pragma unroll
    for (int fn = 0; fn < 4; ++fn)
#pragma unroll
      for (int q = 0; q < 4; ++q) {
        int gm = m0 + wm + fm * 16 + rq + q;
        int gc = c0 + wn + fn * 16 + cl;
        size_t off = ((size_t)(gc >> 6) * 2048 + gm) * 64 + (gc & 63);
        out[off] = __float2bfloat16(acc[fm][fn][q]);
      }
}

// =============== 256-thr core kept for k_a2 ===============
__device__ __forceinline__ void diff_core(
    const bf16s* __restrict__ S, const bf16s* __restrict__ Bsrc,
    int m0, int c0, bf16s* lA, bf16s* lB, f32x4 (&acc)[4][4])
{
  const int tid = threadIdx.x, lane = tid & 63, wave = tid >> 6;
  const int wm = (wave >> 1) * 64, wn = (wave & 1) * 64;
  const f32x4 zero = {0.f, 0.f, 0.f, 0.f};
#pragma unroll
  for (int i = 0; i < 4; ++i)
#pragma unroll
    for (int j = 0; j < 4; ++j) acc[i][j] = zero;
  const int ra = tid >> 3;
  const int cs = ((tid & 7) ^ (ra & 7)) * 8;
  const int rk0 = ((lane >> 4) ^ (lane & 7)) * 8;
  const int rk1 = ((4 + (lane >> 4)) ^ (lane & 7)) * 8;
  for (int k0 = 0; k0 < 2048; k0 += 64) {
#pragma unroll
    for (int i = 0; i < 4; ++i) {
      async_copy16(lA + (size_t)(i * 256 + tid) * 8,
                   S + (size_t)(m0 + i * 32 + ra) * 2048 + k0 + cs);
      async_copy16(lB + (size_t)(i * 256 + tid) * 8,
                   Bsrc + (size_t)(c0 + i * 32 + ra) * 2048 + k0 + cs);
    }
    __syncthreads();
#pragma unroll
    for (int ks = 0; ks < 2; ++ks) {
      const int rk = ks ? rk1 : rk0;
      bf16x8 av[4], bv[4];
#pragma unroll
      for (int f = 0; f < 4; ++f) {
        av[f] = *(const bf16x8*)(lA + (size_t)(wm + f * 16 + (lane & 15)) * 64 + rk);
        bv[f] = *(const bf16x8*)(lB + (size_t)(wn + f * 16 + (lane & 15)) * 64 + rk);
      }
#pragma unroll
      for (int i = 0; i < 4; ++i)
#pragma unroll
        for (int j = 0; j < 4; ++j)
          acc[i][j] = __builtin_amdgcn_mfma_f32_16x16x32_bf16(av[i], bv[j], acc[i][j], 0, 0, 0);
    }
    __syncthreads();
  }
}

__global__ __launch_bounds__(256) void k_a2(
    const bf16s* __restrict__ A, const bf16s* __restrict__ AT, bf16s* A2)
{
  __shared__ bf16s lA[128 * 64];
  __shared__ bf16s lB[128 * 64];
  const int m0 = blockIdx.x * 128, n0 = blockIdx.y * 128;
  f32x4 acc[4][4];
  diff_core(A, AT, m0, n0, lA, lB, acc);
  const int lane = threadIdx.x & 63, wave = threadIdx.x >> 6;
  const int wm = (wave >> 1) * 64, wn = (wave & 1) * 64;
  const int rq = (lane >> 4) * 4, cl = lane & 15;
#pragma unroll
  for (int fm = 0; fm < 4; ++fm)
#pragma unroll
    for (int fn = 0; fn < 4; ++fn)
#pragma unroll
      for (int q = 0; q < 4; ++q) {
        int gm = m0 + wm + fm * 16 + rq + q;
        int gc = n0 + wn + fn * 16 + cl;
        A2[(size_t)gm * 2048 + gc] = __float2bfloat16(2.f * acc[fm][fn][q] - (gm == gc ? 1.f : 0.f));
      }
}

// =============== small GEMM core (gate/cand): K = 6 slots of 64 ===============
template<int BN>
__device__ __forceinline__ void small_core(
    const Slots6& sl, int m0, const bf16s* __restrict__ W,
    bf16s* lA, bf16s* lB, f32x4 (&acc)[4][BN / 32])
{
  const int tid = threadIdx.x, lane = tid & 63, wave = tid >> 6;
  const int wm = (wave >> 1) * 64, wn = (wave & 1) * (BN / 2);
  const f32x4 zero = {0.f, 0.f, 0.f, 0.f};
#pragma unroll
  for (int i = 0; i < 4; ++i)
#pragma unroll
    for (int j = 0; j < BN / 32; ++j) acc[i][j] = zero;

  const int ra = tid >> 3;
  const int cs = ((tid & 7) ^ (ra & 7)) * 8;
  const int rk0 = ((lane >> 4) ^ (lane & 7)) * 8;
  const int rk1 = ((4 + (lane >> 4)) ^ (lane & 7)) * 8;

#pragma unroll
  for (int ks = 0; ks < 6; ++ks) {
    const Slot sd = sl.s[ks];
    if (sd.type == 0) {
      const bf16s* base = (const bf16s*)sd.p0;
#pragma unroll
      for (int i = 0; i < 4; ++i) {
        int row = m0 + i * 32 + ra;
        size_t roff = ((size_t)(row >> 11) * sd.astr0 + sd.trow0 + (row & 2047)) * 64 + cs;
        async_copy16(lA + (size_t)(i * 256 + tid) * 8, base + roff);
      }
    } else if (sd.type == 1) {
#pragma unroll
      for (int i = 0; i < 4; ++i) {
        int row = m0 + i * 32 + ra;
        size_t roff = ((size_t)(row >> 11) * sd.astr0 + sd.trow0 + (row & 2047)) * 64 + cs;
        const float4* q0 = (const float4*)((const float*)sd.p0 + roff);
        float4 a = q0[0], b = q0[1];
        union { bf16x8 v; bf16s h[8]; } u;
        u.h[0] = __float2bfloat16(a.x); u.h[1] = __float2bfloat16(a.y);
        u.h[2] = __float2bfloat16(a.z); u.h[3] = __float2bfloat16(a.w);
        u.h[4] = __float2bfloat16(b.x); u.h[5] = __float2bfloat16(b.y);
        u.h[6] = __float2bfloat16(b.z); u.h[7] = __float2bfloat16(b.w);
        *(bf16x8*)(lA + (size_t)(i * 256 + tid) * 8) = u.v;
      }
    } else {  // bf16 + bf16 add (fp32 accumulate)
#pragma unroll
      for (int i = 0; i < 4; ++i) {
        int row = m0 + i * 32 + ra;
        size_t r0o = ((size_t)(row >> 11) * sd.astr0 + sd.trow0 + (row & 2047)) * 64 + cs;
        size_t r1o = ((size_t)(row >> 11) * sd.astr1 + sd.trow1 + (row & 2047)) * 64 + cs;
        union { bf16x8 v; bf16s h[8]; } a, b, o;
        a.v = *(const bf16x8*)((const bf16s*)sd.p0 + r0o);
        b.v = *(const bf16x8*)((const bf16s*)sd.p1 + r1o);
#pragma unroll
        for (int j = 0; j < 8; ++j)
          o.h[j] = __float2bfloat16(__bfloat162float(a.h[j]) + __bfloat162float(b.h[j]));
        *(bf16x8*)(lA + (size_t)(i * 256 + tid) * 8) = o.v;
      }
    }
#pragma unroll
    for (int i = 0; i < BN / 32; ++i)
      async_copy16(lB + (size_t)(i * 256 + tid) * 8,
                   W + (size_t)(i * 32 + ra) * 384 + ks * 64 + cs);
    __syncthreads();
#pragma unroll
    for (int kss = 0; kss < 2; ++kss) {
      const int rk = kss ? rk1 : rk0;
      bf16x8 av[4], bv[BN / 32];
#pragma unroll
      for (int f = 0; f < 4; ++f)
        av[f] = *(const bf16x8*)(lA + (size_t)(wm + f * 16 + (lane & 15)) * 64 + rk);
#pragma unroll
      for (int f = 0; f < BN / 32; ++f)
        bv[f] = *(const bf16x8*)(lB + (size_t)(wn + f * 16 + (lane & 15)) * 64 + rk);
#pragma unroll
      for (int i = 0; i < 4; ++i)
#pragma unroll
        for (int j = 0; j < BN / 32; ++j)
          acc[i][j] = __builtin_amdgcn_mfma_f32_16x16x32_bf16(av[i], bv[j], acc[i][j], 0, 0, 0);
    }
    __syncthreads();
  }
}

// ---------------- gate (two layers in one launch) ----------------
struct LayerG {
  Slots6 sl; const bf16s* W; const float* bias;
  const float* h; bf16s* zh; bf16s* zhT; float* r;
};
__global__ __launch_bounds__(256) void k_gate(LayerG A, LayerG B, int nA)
{
  __shared__ bf16s lA[128 * 64];
  __shared__ bf16s lB[128 * 64];
  const int bx = blockIdx.x;
  const bool isA = bx < nA;
  const LayerG L = isA ? A : B;
  const int m0 = (isA ? bx : bx - nA) * 128;
  f32x4 acc[4][4];
  small_core<128>(L.sl, m0, L.W, lA, lB, acc);
  const int lane = threadIdx.x & 63, wave = threadIdx.x >> 6;
  const int wm = (wave >> 1) * 64, wn = (wave & 1) * 64;
  const int rq = (lane >> 4) * 4, cl = lane & 15;
#pragma unroll
  for (int fm = 0; fm < 4; ++fm)
#pragma unroll
    for (int fn = 0; fn < 4; ++fn) {
      const int o = wn + fn * 16 + cl;
      const float bias = L.bias[o];
#pragma unroll
      for (int q = 0; q < 4; ++q) {
        size_t gm = (size_t)m0 + wm + fm * 16 + rq + q;
        float s = 1.f / (1.f + expf(-(acc[fm][fn][q] + bias)));
        if (o < 64) {
          float zh = s * L.h[gm * 64 + o];
          L.zh[gm * 64 + o] = __float2bfloat16(zh);
          L.zhT[((size_t)((gm >> 11) * 64 + o)) * 2048 + (gm & 2047)] = __float2bfloat16(zh);
        } else {
          L.r[gm * 64 + (o - 64)] = s;
        }
      }
    }
}

// ---------------- candidate + GRU update (two layers in one launch) ----------------
struct LayerC {
  Slots6 sl; const bf16s* W; const float* bias;
  const float* r; float* h32; bf16s* hT; bf16s* h_bf; float* hid;
  bf16s* x1;                 // layer-0: write x1 = x + h (bf16 rows); null for layer-1
  float* outC;               // layer-1: write outCur; null for layer-0
  const float* x0; int t;
};
__global__ __launch_bounds__(256) void k_cand(LayerC A, LayerC B, int nA)
{
  __shared__ bf16s lA[128 * 64];
  __shared__ bf16s lB[64 * 64];
  const int bx = blockIdx.x;
  const bool isA = bx < nA;
  const LayerC L = isA ? A : B;
  const int m0 = (isA ? bx : bx - nA) * 128;
  f32x4 acc[4][2];
  small_core<64>(L.sl, m0, L.W, lA, lB, acc);
  const int lane = threadIdx.x & 63, wave = threadIdx.x >> 6;
  const int wm = (wave >> 1) * 64, wn = (wave & 1) * 32;
  const int rq = (lane >> 4) * 4, cl = lane & 15;
#pragma unroll
  for (int fm = 0; fm < 4; ++fm)
#pragma unroll
    for (int fn = 0; fn < 2; ++fn) {
      const int d = wn + fn * 16 + cl;
      const float bias = L.bias[d];
#pragma unroll
      for (int q = 0; q < 4; ++q) {
        size_t gm = (size_t)m0 + wm + fm * 16 + rq + q;
        float hc = tanhf(acc[fm][fn][q] + bias);
        float r = L.r[gm * 64 + d];
        float h = L.h32[gm * 64 + d];
        float hn = r * h + (1.f - r) * hc;
        L.h32[gm * 64 + d] = hn;
        int b = (int)(gm >> 11), n = (int)(gm & 2047);
        L.hT[((size_t)(b * 64 + d)) * 2048 + n] = __float2bfloat16(hn);
        L.h_bf[gm * 64 + d] = __float2bfloat16(hn);
        size_t xi = (((size_t)b * kT + L.t) * 2048 + n) * 64 + d;
        if (L.x1) L.x1[gm * 64 + d] = __float2bfloat16(L.x0[xi] + hn);
        if (L.outC) L.outC[xi] = L.x0[xi] + hn;
        if (L.hid) L.hid[gm * 64 + d] = hn;
      }
    }
}

// ---------------- utility kernels ----------------
__global__ __launch_bounds__(256) void transpose_cvt(
    const float* in, bf16s* out, int nrows, int ncols,
    size_t in_ostride, size_t out_ostride)
{
  __shared__ float tile[64][65];
  const int r0 = blockIdx.x * 64, c0 = blockIdx.y * 64;
  in  += (size_t)blockIdx.z * in_ostride;
  out += (size_t)blockIdx.z * out_ostride;
  const int tx = threadIdx.x & 63, ty = threadIdx.x >> 6;
#pragma unroll
  for (int i = 0; i < 64; i += 4)
    tile[ty + i][tx] = in[(size_t)(r0 + ty + i) * ncols + c0 + tx];
  __syncthreads();
#pragma unroll
  for (int i = 0; i < 64; i += 4)
    out[(size_t)(c0 + ty + i) * nrows + r0 + tx] = __float2bfloat16(tile[tx][ty + i]);
}

__global__ __launch_bounds__(256) void k_cvt(const float* in, bf16s* out, int n)
{
  int i = blockIdx.x * 256 + threadIdx.x;
  if (i < n) out[i] = __float2bfloat16(in[i]);
}

__global__ __launch_bounds__(256) void k_repack(
    const float* Wg, const float* Wu, bf16s* WgT, bf16s* WuT)
{
  int idx = blockIdx.x * 256 + threadIdx.x;
  if (idx < 2 * 3 * 128 * 128) {
    int o = idx & 127, cin = (idx >> 7) & 127, k = (idx >> 14) % 3, l = idx / 49152;
    WgT[((size_t)(l * 128 + o)) * 384 + (2 * k + (cin >> 6)) * 64 + (cin & 63)] =
        __float2bfloat16(Wg[idx]);
  }
  if (idx < 2 * 3 * 128 * 64) {
    int o = idx & 63, cin = (idx >> 6) & 127, k = (idx >> 13) % 3, l = idx / 24576;
    WuT[((size_t)(l * 64 + o)) * 384 + (2 * k + (cin >> 6)) * 64 + (cin & 63)] =
        __float2bfloat16(Wu[idx]);
  }
}

__global__ __launch_bounds__(256) void init_layer(
    const float* ist_l, float* h32, bf16s* hT, bf16s* h_bf)
{
  size_t idx = (size_t)blockIdx.x * 256 + threadIdx.x;
  if (idx >= kBND) return;
  int d = (int)(idx & 63);
  size_t row = idx >> 6;
  int n = (int)(row & 2047), b = (int)(row >> 11);
  float h = ist_l[idx];
  h32[idx] = h;
  hT[((size_t)(b * 64 + d)) * 2048 + n] = __float2bfloat16(h);
  h_bf[idx] = __float2bfloat16(h);
}

// ---------------- host orchestration ----------------
extern "C" void kernel_launch(void* const* d_in, const int* in_sizes, int n_in,
                              void* d_out, int out_size, void* d_ws, size_t ws_size,
                              hipStream_t stream)
{
  (void)in_sizes; (void)n_in; (void)out_size; (void)ws_size;
  const float* x   = (const float*)d_in[0];
  const float* ist = (const float*)d_in[1];
  const float* adj = (const float*)d_in[2];
  const float* Wg  = (const float*)d_in[3];
  const float* bg  = (const float*)d_in[4];
  const float* Wu  = (const float*)d_in[5];
  const float* bu  = (const float*)d_in[6];
  float* outCur = (float*)d_out;
  float* outHid = outCur + (size_t)kB * kT * kN * kD;

  char* p = (char*)d_ws;
  auto carve = [&](size_t bytes) { char* q = p; p += (bytes + 255) & ~(size_t)255; return q; };
  bf16s* A_bf  = (bf16s*)carve((size_t)2048 * 2048 * 2);
  bf16s* A2_bf = (bf16s*)carve((size_t)2048 * 2048 * 2);
  bf16s* WgT   = (bf16s*)carve((size_t)2 * 128 * 384 * 2);
  bf16s* WuT   = (bf16s*)carve((size_t)2 * 64 * 384 * 2);
  float* h32b  = (float*)carve(2 * kBND * 4);
  float* r32b  = (float*)carve(2 * kBND * 4);
  bf16s* hTb   = (bf16s*)carve(2 * kBND * 2);
  bf16s* hbfb  = (bf16s*)carve(2 * kBND * 2);
  bf16s* zhTb  = (bf16s*)carve(2 * kBND * 2);
  bf16s* zhbfb = (bf16s*)carve(2 * kBND * 2);
  bf16s* x1b   = (bf16s*)carve(2 * kBND * 2);   // double-buffered by superstep parity
  bf16s* sAh0  = (bf16s*)carve(kBND * 2);
  bf16s* sA2h0 = (bf16s*)carve(kBND * 2);
  bf16s* sAh1  = (bf16s*)carve(kBND * 2);
  bf16s* sA2h1 = (bf16s*)carve(kBND * 2);
  bf16s* sZ0   = (bf16s*)carve(kBND * 2);
  bf16s* sA2Z0 = (bf16s*)carve(kBND * 2);
  bf16s* sZ1   = (bf16s*)carve(kBND * 2);
  bf16s* sA2Z1 = (bf16s*)carve(kBND * 2);
  const size_t xTfull = (size_t)kB * kT * kD * kN * 2;   // 96 MiB
  bf16s* AxF  = (bf16s*)carve(xTfull);
  bf16s* A2xF = (bf16s*)carve(xTfull);
  bf16s* xTh  = (bf16s*)carve(xTfull / 2);
  bf16s* AT_bf = AxF;   // alias: AT dead (after k_a2) before AxF is written

  float* h32_0 = h32b;   float* h32_1 = h32b + kBND;
  float* r32_0 = r32b;   float* r32_1 = r32b + kBND;
  bf16s* hT0 = hTb;      bf16s* hT1 = hTb + kBND;
  bf16s* hbf0 = hbfb;    bf16s* hbf1 = hbfb + kBND;
  bf16s* zhT0 = zhTb;    bf16s* zhT1 = zhTb + kBND;
  bf16s* zhbf0 = zhbfb;  bf16s* zhbf1 = zhbfb + kBND;

  // ---- setup ----
  k_cvt<<<dim3((2048 * 2048 + 255) / 256), 256, 0, stream>>>(adj, A_bf, 2048 * 2048);
  transpose_cvt<<<dim3(32, 32, 1), 256, 0, stream>>>(adj, AT_bf, 2048, 2048, 0, 0);
  k_a2<<<dim3(16, 16, 1), 256, 0, stream>>>(A_bf, AT_bf, A2_bf);
  k_repack<<<dim3(384), 256, 0, stream>>>(Wg, Wu, WgT, WuT);
  init_layer<<<dim3((int)(kBND / 256)), 256, 0, stream>>>(ist, h32_0, hT0, hbf0);
  init_layer<<<dim3((int)(kBND / 256)), 256, 0, stream>>>(ist + kBND, h32_1, hT1, hbf1);

  // ---- batched layer-0 x-diffusion (two b-halves) ----
  for (int h = 0; h < 2; ++h) {
    size_t off = (size_t)h * 8 * kT * 131072;
    transpose_cvt<<<dim3(32, 1, 8 * kT), 256, 0, stream>>>(x + off, xTh, 2048, 64, 131072, 131072);
    k_diff4<<<dim3(16, 96), 512, 0, stream>>>(
        A_bf, A2_bf, DiffSrc{xTh, AxF + off, A2xF + off}, DiffSrc{}, 96);
  }

  auto Sb = [](const void* p0, int astr, int trow) {
    return Slot{p0, nullptr, astr, trow, 0, 0, 0};
  };
  auto Sf = [](const void* p0, int astr, int trow) {
    return Slot{p0, nullptr, astr, trow, 0, 0, 1};
  };
  auto S2 = [](const void* p0, const void* p1, int astr1, int trow1) {
    return Slot{p0, p1, 2048, 0, astr1, trow1, 2};
  };

  // ---- pipelined supersteps: s runs cell(0,s) and cell(1,s-1) ----
  for (int s = 0; s <= kT; ++s) {
    const bool aA = (s < kT), aB = (s >= 1);
    const int tA = s, tB = s - 1;
    const int nA = aA ? 256 : 0, nB = aB ? 256 : 0;
    bf16s* x1cur = x1b + (size_t)(s & 1) * kBND;        // written by cand0 at s
    bf16s* x1prev = x1b + (size_t)((s - 1) & 1) * kBND; // read by layer-1 at s

    // phase-0: diffuse h0 (always; slabs feed gate0 and the x1-combine) and h1
    k_diff4<<<dim3(16, aB ? 16 : 8), 512, 0, stream>>>(
        A_bf, A2_bf, DiffSrc{hT0, sAh0, sA2h0}, DiffSrc{hT1, sAh1, sA2h1}, 8);

    // gate
    {
      LayerG GA = {}, GB = {};
      if (aA) {
        GA.sl.s[0] = Sf(x, kT * 2048, tA * 2048);
        GA.sl.s[1] = Sb(hbf0, 2048, 0);
        GA.sl.s[2] = Sb(AxF, kT * 2048, tA * 2048);
        GA.sl.s[3] = Sb(sAh0, 2048, 0);
        GA.sl.s[4] = Sb(A2xF, kT * 2048, tA * 2048);
        GA.sl.s[5] = Sb(sA2h0, 2048, 0);
        GA.W = WgT; GA.bias = bg; GA.h = h32_0; GA.zh = zhbf0; GA.zhT = zhT0; GA.r = r32_0;
      }
      if (aB) {
        GB.sl.s[0] = Sb(x1prev, 2048, 0);
        GB.sl.s[1] = Sb(hbf1, 2048, 0);
        GB.sl.s[2] = S2(sAh0, AxF, kT * 2048, tB * 2048);   // A@x1 = A@h0 + A@x
        GB.sl.s[3] = Sb(sAh1, 2048, 0);
        GB.sl.s[4] = S2(sA2h0, A2xF, kT * 2048, tB * 2048);
        GB.sl.s[5] = Sb(sA2h1, 2048, 0);
        GB.W = WgT + (size_t)128 * 384; GB.bias = bg + 128;
        GB.h = h32_1; GB.zh = zhbf1; GB.zhT = zhT1; GB.r = r32_1;
      }
      k_gate<<<dim3(nA + nB), 256, 0, stream>>>(GA, GB, nA);
    }

    // phase-1: diffuse zh0 / zh1
    {
      DiffSrc d0{zhT0, sZ0, sA2Z0}, d1{zhT1, sZ1, sA2Z1};
      if (aA && aB)
        k_diff4<<<dim3(16, 16), 512, 0, stream>>>(A_bf, A2_bf, d0, d1, 8);
      else if (aA)
        k_diff4<<<dim3(16, 8), 512, 0, stream>>>(A_bf, A2_bf, d0, d1, 8);
      else
        k_diff4<<<dim3(16, 8), 512, 0, stream>>>(A_bf, A2_bf, d1, d0, 8);
    }

    // candidate + GRU update
    {
      LayerC CA = {}, CB = {};
      if (aA) {
        CA.sl.s[0] = Sf(x, kT * 2048, tA * 2048);
        CA.sl.s[1] = Sb(zhbf0, 2048, 0);
        CA.sl.s[2] = Sb(AxF, kT * 2048, tA * 2048);
        CA.sl.s[3] = Sb(sZ0, 2048, 0);
        CA.sl.s[4] = Sb(A2xF, kT * 2048, tA * 2048);
        CA.sl.s[5] = Sb(sA2Z0, 2048, 0);
        CA.W = WuT; CA.bias = bu; CA.r = r32_0; CA.h32 = h32_0; CA.hT = hT0; CA.h_bf = hbf0;
        CA.hid = (tA == kT - 1) ? outHid : nullptr;
        CA.x1 = x1cur; CA.outC = nullptr; CA.x0 = x; CA.t = tA;
      }
      if (aB) {
        CB.sl.s[0] = Sb(x1prev, 2048, 0);
        CB.sl.s[1] = Sb(zhbf1, 2048, 0);
        CB.sl.s[2] = S2(sAh0, AxF, kT * 2048, tB * 2048);
        CB.sl.s[3] = Sb(sZ1, 2048, 0);
        CB.sl.s[4] = S2(sA2h0, A2xF, kT * 2048, tB * 2048);
        CB.sl.s[5] = Sb(sA2Z1, 2048, 0);
        CB.W = WuT + (size_t)64 * 384; CB.bias = bu + 64;
        CB.r = r32_1; CB.h32 = h32_1; CB.hT = hT1; CB.h_bf = hbf1;
        CB.hid = (tB == kT - 1) ? outHid + kBND : nullptr;
        CB.x1 = nullptr; CB.outC = outCur; CB.x0 = x; CB.t = tB;
      }
      k_cand<<<dim3(nA + nB), 256, 0, stream>>>(CA, CB, nA);
    }
  }
}

// Round 5
// 5091.081 us; speedup vs baseline: 1.0820x; 1.0820x over previous
//
#include <hip/hip_runtime.h>
#include <hip/hip_bf16.h>
#include <math.h>

typedef __bf16 bf16x8 __attribute__((ext_vector_type(8)));
typedef float f32x4 __attribute__((ext_vector_type(4)));
typedef __hip_bfloat16 bf16s;

constexpr int kB = 16, kT = 24, kN = 2048, kD = 64;
constexpr size_t kBND = (size_t)kB * kN * kD;  // 2097152

// slot types: 0 = bf16 direct (global_load_lds), 1 = f32 (cvt), 2 = bf16+bf16 add
struct Slot { const void* p0; const void* p1; int astr0, trow0, astr1, trow1, type; };
struct Slots6 { Slot s[6]; };
struct DiffGrp { const bf16s* src; bf16s* oA; bf16s* oA2; };
struct DiffP { const bf16s* S0; const bf16s* S1; DiffGrp g[4]; int colsPerGrp; };

__device__ __forceinline__ void async_copy16(void* lds, const void* g) {
  __builtin_amdgcn_global_load_lds((const __attribute__((address_space(1))) void*)g,
                                   (__attribute__((address_space(3))) void*)lds,
                                   16, 0, 0);
}

// LDS tiles are [rows][64] bf16 staged linearly; XOR swizzle on 16B chunks:
// source chunk (tid&7)^(row&7), read chunk g^(row&7). Verified 0 conflicts (r3).
// NOTE r4 lesson: 256-thr / 32KB / ~5 blocks/CU beats 512-thr / 48KB operand-
// sharing (k_diff4: MfmaUtil 45->30%, occupancy 31->23%). Keep this shape.

// ---------------- diffusion core: C[128x128] = S[m0:,:2048] @ Bsrc[c0:,:2048]^T ----------------
__device__ __forceinline__ void diff_core(
    const bf16s* __restrict__ S, const bf16s* __restrict__ Bsrc,
    int m0, int c0, bf16s* lA, bf16s* lB, f32x4 (&acc)[4][4])
{
  const int tid = threadIdx.x, lane = tid & 63, wave = tid >> 6;
  const int wm = (wave >> 1) * 64, wn = (wave & 1) * 64;
  const f32x4 zero = {0.f, 0.f, 0.f, 0.f};
#pragma unroll
  for (int i = 0; i < 4; ++i)
#pragma unroll
    for (int j = 0; j < 4; ++j) acc[i][j] = zero;

  const int ra = tid >> 3;
  const int cs = ((tid & 7) ^ (ra & 7)) * 8;          // swizzled source chunk
  const int rk0 = ((lane >> 4) ^ (lane & 7)) * 8;     // swizzled read chunk ks=0
  const int rk1 = ((4 + (lane >> 4)) ^ (lane & 7)) * 8;

  for (int k0 = 0; k0 < 2048; k0 += 64) {
#pragma unroll
    for (int i = 0; i < 4; ++i) {
      async_copy16(lA + (size_t)(i * 256 + tid) * 8,
                   S + (size_t)(m0 + i * 32 + ra) * 2048 + k0 + cs);
      async_copy16(lB + (size_t)(i * 256 + tid) * 8,
                   Bsrc + (size_t)(c0 + i * 32 + ra) * 2048 + k0 + cs);
    }
    __syncthreads();
#pragma unroll
    for (int ks = 0; ks < 2; ++ks) {
      const int rk = ks ? rk1 : rk0;
      bf16x8 av[4], bv[4];
#pragma unroll
      for (int f = 0; f < 4; ++f) {
        av[f] = *(const bf16x8*)(lA + (size_t)(wm + f * 16 + (lane & 15)) * 64 + rk);
        bv[f] = *(const bf16x8*)(lB + (size_t)(wn + f * 16 + (lane & 15)) * 64 + rk);
      }
#pragma unroll
      for (int i = 0; i < 4; ++i)
#pragma unroll
        for (int j = 0; j < 4; ++j)
          acc[i][j] = __builtin_amdgcn_mfma_f32_16x16x32_bf16(av[i], bv[j], acc[i][j], 0, 0, 0);
    }
    __syncthreads();
  }
}

// ---------------- diffusion kernel: up to 4 column groups, 2 supports ----------------
__global__ __launch_bounds__(256) void k_diff(DiffP p)
{
  __shared__ bf16s lA[128 * 64];
  __shared__ bf16s lB[128 * 64];
  const int mi = blockIdx.x;
  const bf16s* S = (mi >> 4) ? p.S1 : p.S0;
  const int m0 = (mi & 15) * 128;
  const int ybpg = p.colsPerGrp >> 7;
  const int grp = blockIdx.y / ybpg;
  const int c0 = (blockIdx.y - grp * ybpg) * 128;
  const DiffGrp G = p.g[grp];

  f32x4 acc[4][4];
  diff_core(S, G.src, m0, c0, lA, lB, acc);

  bf16s* out = (mi >> 4) ? G.oA2 : G.oA;
  const int lane = threadIdx.x & 63, wave = threadIdx.x >> 6;
  const int wm = (wave >> 1) * 64, wn = (wave & 1) * 64;
  const int rq = (lane >> 4) * 4, cl = lane & 15;
#pragma unroll
  for (int fm = 0; fm < 4; ++fm)
#pragma unroll
    for (int fn = 0; fn < 4; ++fn)
#pragma unroll
      for (int q = 0; q < 4; ++q) {
        int gm = m0 + wm + fm * 16 + rq + q;
        int gc = c0 + wn + fn * 16 + cl;
        size_t off = ((size_t)(gc >> 6) * 2048 + gm) * 64 + (gc & 63);
        out[off] = __float2bfloat16(acc[fm][fn][q]);
      }
}

// ---------------- setup: A2 = 2*A@A - I ----------------
__global__ __launch_bounds__(256) void k_a2(
    const bf16s* __restrict__ A, const bf16s* __restrict__ AT, bf16s* A2)
{
  __shared__ bf16s lA[128 * 64];
  __shared__ bf16s lB[128 * 64];
  const int m0 = blockIdx.x * 128, n0 = blockIdx.y * 128;
  f32x4 acc[4][4];
  diff_core(A, AT, m0, n0, lA, lB, acc);
  const int lane = threadIdx.x & 63, wave = threadIdx.x >> 6;
  const int wm = (wave >> 1) * 64, wn = (wave & 1) * 64;
  const int rq = (lane >> 4) * 4, cl = lane & 15;
#pragma unroll
  for (int fm = 0; fm < 4; ++fm)
#pragma unroll
    for (int fn = 0; fn < 4; ++fn)
#pragma unroll
      for (int q = 0; q < 4; ++q) {
        int gm = m0 + wm + fm * 16 + rq + q;
        int gc = n0 + wn + fn * 16 + cl;
        A2[(size_t)gm * 2048 + gc] = __float2bfloat16(2.f * acc[fm][fn][q] - (gm == gc ? 1.f : 0.f));
      }
}

// =============== small GEMM core (gate/cand): K = 6 slots of 64 ===============
template<int BN>
__device__ __forceinline__ void small_core(
    const Slots6& sl, int m0, const bf16s* __restrict__ W,
    bf16s* lA, bf16s* lB, f32x4 (&acc)[4][BN / 32])
{
  const int tid = threadIdx.x, lane = tid & 63, wave = tid >> 6;
  const int wm = (wave >> 1) * 64, wn = (wave & 1) * (BN / 2);
  const f32x4 zero = {0.f, 0.f, 0.f, 0.f};
#pragma unroll
  for (int i = 0; i < 4; ++i)
#pragma unroll
    for (int j = 0; j < BN / 32; ++j) acc[i][j] = zero;

  const int ra = tid >> 3;
  const int cs = ((tid & 7) ^ (ra & 7)) * 8;
  const int rk0 = ((lane >> 4) ^ (lane & 7)) * 8;
  const int rk1 = ((4 + (lane >> 4)) ^ (lane & 7)) * 8;

#pragma unroll
  for (int ks = 0; ks < 6; ++ks) {
    const Slot sd = sl.s[ks];
    if (sd.type == 0) {
      const bf16s* base = (const bf16s*)sd.p0;
#pragma unroll
      for (int i = 0; i < 4; ++i) {
        int row = m0 + i * 32 + ra;
        size_t roff = ((size_t)(row >> 11) * sd.astr0 + sd.trow0 + (row & 2047)) * 64 + cs;
        async_copy16(lA + (size_t)(i * 256 + tid) * 8, base + roff);
      }
    } else if (sd.type == 1) {
#pragma unroll
      for (int i = 0; i < 4; ++i) {
        int row = m0 + i * 32 + ra;
        size_t roff = ((size_t)(row >> 11) * sd.astr0 + sd.trow0 + (row & 2047)) * 64 + cs;
        const float4* q0 = (const float4*)((const float*)sd.p0 + roff);
        float4 a = q0[0], b = q0[1];
        union { bf16x8 v; bf16s h[8]; } u;
        u.h[0] = __float2bfloat16(a.x); u.h[1] = __float2bfloat16(a.y);
        u.h[2] = __float2bfloat16(a.z); u.h[3] = __float2bfloat16(a.w);
        u.h[4] = __float2bfloat16(b.x); u.h[5] = __float2bfloat16(b.y);
        u.h[6] = __float2bfloat16(b.z); u.h[7] = __float2bfloat16(b.w);
        *(bf16x8*)(lA + (size_t)(i * 256 + tid) * 8) = u.v;
      }
    } else {  // bf16 + bf16 add (fp32 accumulate)
#pragma unroll
      for (int i = 0; i < 4; ++i) {
        int row = m0 + i * 32 + ra;
        size_t r0o = ((size_t)(row >> 11) * sd.astr0 + sd.trow0 + (row & 2047)) * 64 + cs;
        size_t r1o = ((size_t)(row >> 11) * sd.astr1 + sd.trow1 + (row & 2047)) * 64 + cs;
        union { bf16x8 v; bf16s h[8]; } a, b, o;
        a.v = *(const bf16x8*)((const bf16s*)sd.p0 + r0o);
        b.v = *(const bf16x8*)((const bf16s*)sd.p1 + r1o);
#pragma unroll
        for (int j = 0; j < 8; ++j)
          o.h[j] = __float2bfloat16(__bfloat162float(a.h[j]) + __bfloat162float(b.h[j]));
        *(bf16x8*)(lA + (size_t)(i * 256 + tid) * 8) = o.v;
      }
    }
#pragma unroll
    for (int i = 0; i < BN / 32; ++i)
      async_copy16(lB + (size_t)(i * 256 + tid) * 8,
                   W + (size_t)(i * 32 + ra) * 384 + ks * 64 + cs);
    __syncthreads();
#pragma unroll
    for (int kss = 0; kss < 2; ++kss) {
      const int rk = kss ? rk1 : rk0;
      bf16x8 av[4], bv[BN / 32];
#pragma unroll
      for (int f = 0; f < 4; ++f)
        av[f] = *(const bf16x8*)(lA + (size_t)(wm + f * 16 + (lane & 15)) * 64 + rk);
#pragma unroll
      for (int f = 0; f < BN / 32; ++f)
        bv[f] = *(const bf16x8*)(lB + (size_t)(wn + f * 16 + (lane & 15)) * 64 + rk);
#pragma unroll
      for (int i = 0; i < 4; ++i)
#pragma unroll
        for (int j = 0; j < BN / 32; ++j)
          acc[i][j] = __builtin_amdgcn_mfma_f32_16x16x32_bf16(av[i], bv[j], acc[i][j], 0, 0, 0);
    }
    __syncthreads();
  }
}

// ---------------- gate (two layers in one launch) ----------------
struct LayerG {
  Slots6 sl; const bf16s* W; const float* bias;
  const float* h; bf16s* zh; bf16s* zhT; float* r;
};
__global__ __launch_bounds__(256) void k_gate(LayerG A, LayerG B, int nA)
{
  __shared__ bf16s lA[128 * 64];
  __shared__ bf16s lB[128 * 64];
  const int bx = blockIdx.x;
  const bool isA = bx < nA;
  const LayerG L = isA ? A : B;
  const int m0 = (isA ? bx : bx - nA) * 128;
  f32x4 acc[4][4];
  small_core<128>(L.sl, m0, L.W, lA, lB, acc);
  const int lane = threadIdx.x & 63, wave = threadIdx.x >> 6;
  const int wm = (wave >> 1) * 64, wn = (wave & 1) * 64;
  const int rq = (lane >> 4) * 4, cl = lane & 15;
#pragma unroll
  for (int fm = 0; fm < 4; ++fm)
#pragma unroll
    for (int fn = 0; fn < 4; ++fn) {
      const int o = wn + fn * 16 + cl;
      const float bias = L.bias[o];
#pragma unroll
      for (int q = 0; q < 4; ++q) {
        size_t gm = (size_t)m0 + wm + fm * 16 + rq + q;
        float s = 1.f / (1.f + expf(-(acc[fm][fn][q] + bias)));
        if (o < 64) {
          float zh = s * L.h[gm * 64 + o];
          L.zh[gm * 64 + o] = __float2bfloat16(zh);
          L.zhT[((size_t)((gm >> 11) * 64 + o)) * 2048 + (gm & 2047)] = __float2bfloat16(zh);
        } else {
          L.r[gm * 64 + (o - 64)] = s;
        }
      }
    }
}

// ---------------- candidate + GRU update (two layers in one launch) ----------------
struct LayerC {
  Slots6 sl; const bf16s* W; const float* bias;
  const float* r; float* h32; bf16s* hT; bf16s* h_bf; float* hid;
  bf16s* x1;                 // layer-0: write x1 = x + h (bf16 rows); null for layer-1
  float* outC;               // layer-1: write outCur; null for layer-0
  const float* x0; int t;
};
__global__ __launch_bounds__(256) void k_cand(LayerC A, LayerC B, int nA)
{
  __shared__ bf16s lA[128 * 64];
  __shared__ bf16s lB[64 * 64];
  const int bx = blockIdx.x;
  const bool isA = bx < nA;
  const LayerC L = isA ? A : B;
  const int m0 = (isA ? bx : bx - nA) * 128;
  f32x4 acc[4][2];
  small_core<64>(L.sl, m0, L.W, lA, lB, acc);
  const int lane = threadIdx.x & 63, wave = threadIdx.x >> 6;
  const int wm = (wave >> 1) * 64, wn = (wave & 1) * 32;
  const int rq = (lane >> 4) * 4, cl = lane & 15;
#pragma unroll
  for (int fm = 0; fm < 4; ++fm)
#pragma unroll
    for (int fn = 0; fn < 2; ++fn) {
      const int d = wn + fn * 16 + cl;
      const float bias = L.bias[d];
#pragma unroll
      for (int q = 0; q < 4; ++q) {
        size_t gm = (size_t)m0 + wm + fm * 16 + rq + q;
        float hc = tanhf(acc[fm][fn][q] + bias);
        float r = L.r[gm * 64 + d];
        float h = L.h32[gm * 64 + d];
        float hn = r * h + (1.f - r) * hc;
        L.h32[gm * 64 + d] = hn;
        int b = (int)(gm >> 11), n = (int)(gm & 2047);
        L.hT[((size_t)(b * 64 + d)) * 2048 + n] = __float2bfloat16(hn);
        L.h_bf[gm * 64 + d] = __float2bfloat16(hn);
        size_t xi = (((size_t)b * kT + L.t) * 2048 + n) * 64 + d;
        if (L.x1) L.x1[gm * 64 + d] = __float2bfloat16(L.x0[xi] + hn);
        if (L.outC) L.outC[xi] = L.x0[xi] + hn;
        if (L.hid) L.hid[gm * 64 + d] = hn;
      }
    }
}

// ---------------- utility kernels ----------------
__global__ __launch_bounds__(256) void transpose_cvt(
    const float* in, bf16s* out, int nrows, int ncols,
    size_t in_ostride, size_t out_ostride)
{
  __shared__ float tile[64][65];
  const int r0 = blockIdx.x * 64, c0 = blockIdx.y * 64;
  in  += (size_t)blockIdx.z * in_ostride;
  out += (size_t)blockIdx.z * out_ostride;
  const int tx = threadIdx.x & 63, ty = threadIdx.x >> 6;
#pragma unroll
  for (int i = 0; i < 64; i += 4)
    tile[ty + i][tx] = in[(size_t)(r0 + ty + i) * ncols + c0 + tx];
  __syncthreads();
#pragma unroll
  for (int i = 0; i < 64; i += 4)
    out[(size_t)(c0 + ty + i) * nrows + r0 + tx] = __float2bfloat16(tile[tx][ty + i]);
}

__global__ __launch_bounds__(256) void k_cvt(const float* in, bf16s* out, int n)
{
  int i = blockIdx.x * 256 + threadIdx.x;
  if (i < n) out[i] = __float2bfloat16(in[i]);
}

__global__ __launch_bounds__(256) void k_repack(
    const float* Wg, const float* Wu, bf16s* WgT, bf16s* WuT)
{
  int idx = blockIdx.x * 256 + threadIdx.x;
  if (idx < 2 * 3 * 128 * 128) {
    int o = idx & 127, cin = (idx >> 7) & 127, k = (idx >> 14) % 3, l = idx / 49152;
    WgT[((size_t)(l * 128 + o)) * 384 + (2 * k + (cin >> 6)) * 64 + (cin & 63)] =
        __float2bfloat16(Wg[idx]);
  }
  if (idx < 2 * 3 * 128 * 64) {
    int o = idx & 63, cin = (idx >> 6) & 127, k = (idx >> 13) % 3, l = idx / 24576;
    WuT[((size_t)(l * 64 + o)) * 384 + (2 * k + (cin >> 6)) * 64 + (cin & 63)] =
        __float2bfloat16(Wu[idx]);
  }
}

__global__ __launch_bounds__(256) void init_layer(
    const float* ist_l, float* h32, bf16s* hT, bf16s* h_bf)
{
  size_t idx = (size_t)blockIdx.x * 256 + threadIdx.x;
  if (idx >= kBND) return;
  int d = (int)(idx & 63);
  size_t row = idx >> 6;
  int n = (int)(row & 2047), b = (int)(row >> 11);
  float h = ist_l[idx];
  h32[idx] = h;
  hT[((size_t)(b * 64 + d)) * 2048 + n] = __float2bfloat16(h);
  h_bf[idx] = __float2bfloat16(h);
}

// ---------------- host orchestration ----------------
extern "C" void kernel_launch(void* const* d_in, const int* in_sizes, int n_in,
                              void* d_out, int out_size, void* d_ws, size_t ws_size,
                              hipStream_t stream)
{
  (void)in_sizes; (void)n_in; (void)out_size; (void)ws_size;
  const float* x   = (const float*)d_in[0];
  const float* ist = (const float*)d_in[1];
  const float* adj = (const float*)d_in[2];
  const float* Wg  = (const float*)d_in[3];
  const float* bg  = (const float*)d_in[4];
  const float* Wu  = (const float*)d_in[5];
  const float* bu  = (const float*)d_in[6];
  float* outCur = (float*)d_out;
  float* outHid = outCur + (size_t)kB * kT * kN * kD;

  char* p = (char*)d_ws;
  auto carve = [&](size_t bytes) { char* q = p; p += (bytes + 255) & ~(size_t)255; return q; };
  bf16s* A_bf  = (bf16s*)carve((size_t)2048 * 2048 * 2);
  bf16s* A2_bf = (bf16s*)carve((size_t)2048 * 2048 * 2);
  bf16s* WgT   = (bf16s*)carve((size_t)2 * 128 * 384 * 2);
  bf16s* WuT   = (bf16s*)carve((size_t)2 * 64 * 384 * 2);
  float* h32b  = (float*)carve(2 * kBND * 4);
  float* r32b  = (float*)carve(2 * kBND * 4);
  bf16s* hTb   = (bf16s*)carve(2 * kBND * 2);
  bf16s* hbfb  = (bf16s*)carve(2 * kBND * 2);
  bf16s* zhTb  = (bf16s*)carve(2 * kBND * 2);
  bf16s* zhbfb = (bf16s*)carve(2 * kBND * 2);
  bf16s* x1b   = (bf16s*)carve(2 * kBND * 2);   // double-buffered by superstep parity
  bf16s* sAh0  = (bf16s*)carve(kBND * 2);
  bf16s* sA2h0 = (bf16s*)carve(kBND * 2);
  bf16s* sAh1  = (bf16s*)carve(kBND * 2);
  bf16s* sA2h1 = (bf16s*)carve(kBND * 2);
  bf16s* sZ0   = (bf16s*)carve(kBND * 2);
  bf16s* sA2Z0 = (bf16s*)carve(kBND * 2);
  bf16s* sZ1   = (bf16s*)carve(kBND * 2);
  bf16s* sA2Z1 = (bf16s*)carve(kBND * 2);
  const size_t xTfull = (size_t)kB * kT * kD * kN * 2;   // 96 MiB
  bf16s* AxF  = (bf16s*)carve(xTfull);
  bf16s* A2xF = (bf16s*)carve(xTfull);
  bf16s* xTh  = (bf16s*)carve(xTfull / 2);
  bf16s* AT_bf = AxF;   // alias: AT dead (after k_a2) before AxF is written

  float* h32_0 = h32b;   float* h32_1 = h32b + kBND;
  float* r32_0 = r32b;   float* r32_1 = r32b + kBND;
  bf16s* hT0 = hTb;      bf16s* hT1 = hTb + kBND;
  bf16s* hbf0 = hbfb;    bf16s* hbf1 = hbfb + kBND;
  bf16s* zhT0 = zhTb;    bf16s* zhT1 = zhTb + kBND;
  bf16s* zhbf0 = zhbfb;  bf16s* zhbf1 = zhbfb + kBND;

  // ---- setup ----
  k_cvt<<<dim3((2048 * 2048 + 255) / 256), 256, 0, stream>>>(adj, A_bf, 2048 * 2048);
  transpose_cvt<<<dim3(32, 32, 1), 256, 0, stream>>>(adj, AT_bf, 2048, 2048, 0, 0);
  k_a2<<<dim3(16, 16, 1), 256, 0, stream>>>(A_bf, AT_bf, A2_bf);
  k_repack<<<dim3(384), 256, 0, stream>>>(Wg, Wu, WgT, WuT);
  init_layer<<<dim3((int)(kBND / 256)), 256, 0, stream>>>(ist, h32_0, hT0, hbf0);
  init_layer<<<dim3((int)(kBND / 256)), 256, 0, stream>>>(ist + kBND, h32_1, hT1, hbf1);

  // ---- batched layer-0 x-diffusion (two b-halves) ----
  for (int h = 0; h < 2; ++h) {
    size_t off = (size_t)h * 8 * kT * 131072;
    transpose_cvt<<<dim3(32, 1, 8 * kT), 256, 0, stream>>>(x + off, xTh, 2048, 64, 131072, 131072);
    DiffP dp; dp.S0 = A_bf; dp.S1 = A2_bf; dp.colsPerGrp = 12288;
    dp.g[0] = DiffGrp{xTh, AxF + off, A2xF + off};
    dp.g[1] = dp.g[2] = dp.g[3] = DiffGrp{nullptr, nullptr, nullptr};
    k_diff<<<dim3(32, 96), 256, 0, stream>>>(dp);
  }

  auto Sb = [](const void* p0, int astr, int trow) {
    return Slot{p0, nullptr, astr, trow, 0, 0, 0};
  };
  auto Sf = [](const void* p0, int astr, int trow) {
    return Slot{p0, nullptr, astr, trow, 0, 0, 1};
  };
  auto S2 = [](const void* p0, const void* p1, int astr1, int trow1) {
    return Slot{p0, p1, 2048, 0, astr1, trow1, 2};
  };

  // ---- pipelined supersteps: s runs cell(0,s) and cell(1,s-1) ----
  for (int s = 0; s <= kT; ++s) {
    const bool aA = (s < kT), aB = (s >= 1);
    const int tA = s, tB = s - 1;
    const int nA = aA ? 256 : 0, nB = aB ? 256 : 0;
    bf16s* x1cur = x1b + (size_t)(s & 1) * kBND;        // written by cand0 at s
    bf16s* x1prev = x1b + (size_t)((s - 1) & 1) * kBND; // read by layer-1 at s

    // phase-0: diffuse h0 (always: feeds gate0 AND layer-1's x1 algebra) and h1
    {
      DiffP dp; dp.S0 = A_bf; dp.S1 = A2_bf; dp.colsPerGrp = 1024;
      int ng = 0;
      dp.g[ng++] = DiffGrp{hT0, sAh0, sA2h0};
      if (aB) dp.g[ng++] = DiffGrp{hT1, sAh1, sA2h1};
      for (int i = ng; i < 4; ++i) dp.g[i] = DiffGrp{nullptr, nullptr, nullptr};
      k_diff<<<dim3(32, 8 * ng), 256, 0, stream>>>(dp);
    }

    // gate
    {
      LayerG GA = {}, GB = {};
      if (aA) {
        GA.sl.s[0] = Sf(x, kT * 2048, tA * 2048);
        GA.sl.s[1] = Sb(hbf0, 2048, 0);
        GA.sl.s[2] = Sb(AxF, kT * 2048, tA * 2048);
        GA.sl.s[3] = Sb(sAh0, 2048, 0);
        GA.sl.s[4] = Sb(A2xF, kT * 2048, tA * 2048);
        GA.sl.s[5] = Sb(sA2h0, 2048, 0);
        GA.W = WgT; GA.bias = bg; GA.h = h32_0; GA.zh = zhbf0; GA.zhT = zhT0; GA.r = r32_0;
      }
      if (aB) {
        GB.sl.s[0] = Sb(x1prev, 2048, 0);
        GB.sl.s[1] = Sb(hbf1, 2048, 0);
        GB.sl.s[2] = S2(sAh0, AxF, kT * 2048, tB * 2048);   // A@x1 = A@h0 + A@x
        GB.sl.s[3] = Sb(sAh1, 2048, 0);
        GB.sl.s[4] = S2(sA2h0, A2xF, kT * 2048, tB * 2048);
        GB.sl.s[5] = Sb(sA2h1, 2048, 0);
        GB.W = WgT + (size_t)128 * 384; GB.bias = bg + 128;
        GB.h = h32_1; GB.zh = zhbf1; GB.zhT = zhT1; GB.r = r32_1;
      }
      k_gate<<<dim3(nA + nB), 256, 0, stream>>>(GA, GB, nA);
    }

    // phase-1: diffuse zh0 / zh1
    {
      DiffP dp; dp.S0 = A_bf; dp.S1 = A2_bf; dp.colsPerGrp = 1024;
      int ng = 0;
      if (aA) dp.g[ng++] = DiffGrp{zhT0, sZ0, sA2Z0};
      if (aB) dp.g[ng++] = DiffGrp{zhT1, sZ1, sA2Z1};
      for (int i = ng; i < 4; ++i) dp.g[i] = DiffGrp{nullptr, nullptr, nullptr};
      k_diff<<<dim3(32, 8 * ng), 256, 0, stream>>>(dp);
    }

    // candidate + GRU update
    {
      LayerC CA = {}, CB = {};
      if (aA) {
        CA.sl.s[0] = Sf(x, kT * 2048, tA * 2048);
        CA.sl.s[1] = Sb(zhbf0, 2048, 0);
        CA.sl.s[2] = Sb(AxF, kT * 2048, tA * 2048);
        CA.sl.s[3] = Sb(sZ0, 2048, 0);
        CA.sl.s[4] = Sb(A2xF, kT * 2048, tA * 2048);
        CA.sl.s[5] = Sb(sA2Z0, 2048, 0);
        CA.W = WuT; CA.bias = bu; CA.r = r32_0; CA.h32 = h32_0; CA.hT = hT0; CA.h_bf = hbf0;
        CA.hid = (tA == kT - 1) ? outHid : nullptr;
        CA.x1 = x1cur; CA.outC = nullptr; CA.x0 = x; CA.t = tA;
      }
      if (aB) {
        CB.sl.s[0] = Sb(x1prev, 2048, 0);
        CB.sl.s[1] = Sb(zhbf1, 2048, 0);
        CB.sl.s[2] = S2(sAh0, AxF, kT * 2048, tB * 2048);
        CB.sl.s[3] = Sb(sZ1, 2048, 0);
        CB.sl.s[4] = S2(sA2h0, A2xF, kT * 2048, tB * 2048);
        CB.sl.s[5] = Sb(sA2Z1, 2048, 0);
        CB.W = WuT + (size_t)64 * 384; CB.bias = bu + 64;
        CB.r = r32_1; CB.h32 = h32_1; CB.hT = hT1; CB.h_bf = hbf1;
        CB.hid = (tB == kT - 1) ? outHid + kBND : nullptr;
        CB.x1 = nullptr; CB.outC = outCur; CB.x0 = x; CB.t = tB;
      }
      k_cand<<<dim3(nA + nB), 256, 0, stream>>>(CA, CB, nA);
    }
  }
}